// Round 2
// baseline (11426.156 us; speedup 1.0000x reference)
//
#include <hip/hip_runtime.h>
#include <hip/hip_bf16.h>
#include <math.h>

#define D_DIM 1024
#define B_ROWS 4096
#define M_ROWS 32768
#define TOPK 8
#define NSTRIPS 16
#define STRIP_COLS (M_ROWS / NSTRIPS)   // 2048
#define SIM_SCALE (1.0 / 32.0)          // 1/(sqrt(1024)*TEMP), exact pow2

#define BM 128
#define BN 64
#define BK 32

// ---------------------------------------------------------------------------
// out[r][n] = sum_d X[r][d]*W[n][d] + bias[n], fp64 accumulation over fp32
// inputs, rounded once to fp32 on store. Used for q and K (selection path).
// ---------------------------------------------------------------------------
__global__ __launch_bounds__(256) void gemm_nt_bias_f64(
    const float* __restrict__ X, const float* __restrict__ W,
    const float* __restrict__ bias, float* __restrict__ out)
{
  __shared__ float sA[BK][BM + 4];
  __shared__ float sB[BK][BN + 4];
  const int tid = threadIdx.x;
  const int tx = tid & 15, ty = tid >> 4;
  const int row0 = blockIdx.x * BM;
  const int col0 = blockIdx.y * BN;
  const int lr = tid >> 3;         // 0..31
  const int lc = (tid & 7) << 2;   // 0,4,...,28

  double acc[2][4][4];
#pragma unroll
  for (int g = 0; g < 2; ++g)
#pragma unroll
    for (int i = 0; i < 4; ++i)
#pragma unroll
      for (int j = 0; j < 4; ++j) acc[g][i][j] = 0.0;

  for (int k0 = 0; k0 < D_DIM; k0 += BK) {
#pragma unroll
    for (int rr = 0; rr < 4; ++rr) {
      const float4 v = *(const float4*)(X + (size_t)(row0 + lr + 32 * rr) * D_DIM + k0 + lc);
      sA[lc + 0][lr + 32 * rr] = v.x;
      sA[lc + 1][lr + 32 * rr] = v.y;
      sA[lc + 2][lr + 32 * rr] = v.z;
      sA[lc + 3][lr + 32 * rr] = v.w;
    }
#pragma unroll
    for (int rr = 0; rr < 2; ++rr) {
      const float4 v = *(const float4*)(W + (size_t)(col0 + lr + 32 * rr) * D_DIM + k0 + lc);
      sB[lc + 0][lr + 32 * rr] = v.x;
      sB[lc + 1][lr + 32 * rr] = v.y;
      sB[lc + 2][lr + 32 * rr] = v.z;
      sB[lc + 3][lr + 32 * rr] = v.w;
    }
    __syncthreads();
#pragma unroll
    for (int kk = 0; kk < BK; ++kk) {
      const float4 A0 = *(const float4*)&sA[kk][ty * 4];
      const float4 A1 = *(const float4*)&sA[kk][64 + ty * 4];
      const float4 Bv = *(const float4*)&sB[kk][tx * 4];
      const double a0[4] = {A0.x, A0.y, A0.z, A0.w};
      const double a1[4] = {A1.x, A1.y, A1.z, A1.w};
      const double bb[4] = {Bv.x, Bv.y, Bv.z, Bv.w};
#pragma unroll
      for (int i = 0; i < 4; ++i)
#pragma unroll
        for (int j = 0; j < 4; ++j) {
          acc[0][i][j] = fma(a0[i], bb[j], acc[0][i][j]);
          acc[1][i][j] = fma(a1[i], bb[j], acc[1][i][j]);
        }
    }
    __syncthreads();
  }
  const float4 bv4 = *(const float4*)(bias + col0 + tx * 4);
  const double bb[4] = {bv4.x, bv4.y, bv4.z, bv4.w};
#pragma unroll
  for (int g = 0; g < 2; ++g)
#pragma unroll
    for (int i = 0; i < 4; ++i) {
      float4 o;
      o.x = (float)(acc[g][i][0] + bb[0]);
      o.y = (float)(acc[g][i][1] + bb[1]);
      o.z = (float)(acc[g][i][2] + bb[2]);
      o.w = (float)(acc[g][i][3] + bb[3]);
      *(float4*)(out + (size_t)(row0 + g * 64 + ty * 4 + i) * D_DIM + col0 + tx * 4) = o;
    }
}

// ---------------------------------------------------------------------------
// fp32 version for V (values only; 2% output threshold, fp32 error ~1e-6).
// ---------------------------------------------------------------------------
__global__ __launch_bounds__(256) void gemm_nt_bias_f32(
    const float* __restrict__ X, const float* __restrict__ W,
    const float* __restrict__ bias, float* __restrict__ out)
{
  __shared__ float sA[BK][BM + 4];
  __shared__ float sB[BK][BN + 4];
  const int tid = threadIdx.x;
  const int tx = tid & 15, ty = tid >> 4;
  const int row0 = blockIdx.x * BM;
  const int col0 = blockIdx.y * BN;
  const int lr = tid >> 3;
  const int lc = (tid & 7) << 2;

  float acc[2][4][4];
#pragma unroll
  for (int g = 0; g < 2; ++g)
#pragma unroll
    for (int i = 0; i < 4; ++i)
#pragma unroll
      for (int j = 0; j < 4; ++j) acc[g][i][j] = 0.f;

  for (int k0 = 0; k0 < D_DIM; k0 += BK) {
#pragma unroll
    for (int rr = 0; rr < 4; ++rr) {
      const float4 v = *(const float4*)(X + (size_t)(row0 + lr + 32 * rr) * D_DIM + k0 + lc);
      sA[lc + 0][lr + 32 * rr] = v.x;
      sA[lc + 1][lr + 32 * rr] = v.y;
      sA[lc + 2][lr + 32 * rr] = v.z;
      sA[lc + 3][lr + 32 * rr] = v.w;
    }
#pragma unroll
    for (int rr = 0; rr < 2; ++rr) {
      const float4 v = *(const float4*)(W + (size_t)(col0 + lr + 32 * rr) * D_DIM + k0 + lc);
      sB[lc + 0][lr + 32 * rr] = v.x;
      sB[lc + 1][lr + 32 * rr] = v.y;
      sB[lc + 2][lr + 32 * rr] = v.z;
      sB[lc + 3][lr + 32 * rr] = v.w;
    }
    __syncthreads();
#pragma unroll
    for (int kk = 0; kk < BK; ++kk) {
      const float4 A0 = *(const float4*)&sA[kk][ty * 4];
      const float4 A1 = *(const float4*)&sA[kk][64 + ty * 4];
      const float4 Bv = *(const float4*)&sB[kk][tx * 4];
      const float a0[4] = {A0.x, A0.y, A0.z, A0.w};
      const float a1[4] = {A1.x, A1.y, A1.z, A1.w};
      const float bb[4] = {Bv.x, Bv.y, Bv.z, Bv.w};
#pragma unroll
      for (int i = 0; i < 4; ++i)
#pragma unroll
        for (int j = 0; j < 4; ++j) {
          acc[0][i][j] = fmaf(a0[i], bb[j], acc[0][i][j]);
          acc[1][i][j] = fmaf(a1[i], bb[j], acc[1][i][j]);
        }
    }
    __syncthreads();
  }
  const float4 bv4 = *(const float4*)(bias + col0 + tx * 4);
  const float bb[4] = {bv4.x, bv4.y, bv4.z, bv4.w};
#pragma unroll
  for (int g = 0; g < 2; ++g)
#pragma unroll
    for (int i = 0; i < 4; ++i) {
      float4 o;
      o.x = acc[g][i][0] + bb[0];
      o.y = acc[g][i][1] + bb[1];
      o.z = acc[g][i][2] + bb[2];
      o.w = acc[g][i][3] + bb[3];
      *(float4*)(out + (size_t)(row0 + g * 64 + ty * 4 + i) * D_DIM + col0 + tx * 4) = o;
    }
}

// ---------------------------------------------------------------------------
// Fused sims + per-strip top-8, fp64 accumulation. 128 rows x 32-col chunks
// (BN=32 so the f64 tile fits LDS: 16.9+4.6+33.8 = 55.3 KB). Values stay
// double through selection so 1e-7 gaps can't collapse into false ties.
// Strict >, ascending index scan => lax.top_k lower-index-first ties.
// ---------------------------------------------------------------------------
#define SBN 32
__global__ __launch_bounds__(256) void sims_topk_f64(
    const float* __restrict__ Q, const float* __restrict__ Km,
    double* __restrict__ part_v, int* __restrict__ part_i)
{
  __shared__ float sA[BK][BM + 4];
  __shared__ float sB[BK][SBN + 4];
  __shared__ double tile[BM][SBN + 1];
  const int tid = threadIdx.x;
  const int tx = tid & 7, ty = tid >> 3;     // 8 x 32 thread grid, 4x4 each
  const int row0 = blockIdx.x * BM;
  const int strip = blockIdx.y;
  const int lr = tid >> 3;                   // 0..31
  const int lc = (tid & 7) << 2;             // 0..28

  double tv[TOPK];
  int ti_[TOPK];
#pragma unroll
  for (int p = 0; p < TOPK; ++p) { tv[p] = -1e300; ti_[p] = 0; }

  for (int ch = 0; ch < STRIP_COLS / SBN; ++ch) {
    const int col0 = strip * STRIP_COLS + ch * SBN;
    double acc[4][4];
#pragma unroll
    for (int i = 0; i < 4; ++i)
#pragma unroll
      for (int j = 0; j < 4; ++j) acc[i][j] = 0.0;

    for (int k0 = 0; k0 < D_DIM; k0 += BK) {
#pragma unroll
      for (int rr = 0; rr < 4; ++rr) {
        const float4 v = *(const float4*)(Q + (size_t)(row0 + lr + 32 * rr) * D_DIM + k0 + lc);
        sA[lc + 0][lr + 32 * rr] = v.x;
        sA[lc + 1][lr + 32 * rr] = v.y;
        sA[lc + 2][lr + 32 * rr] = v.z;
        sA[lc + 3][lr + 32 * rr] = v.w;
      }
      {
        const float4 v = *(const float4*)(Km + (size_t)(col0 + lr) * D_DIM + k0 + lc);
        sB[lc + 0][lr] = v.x;
        sB[lc + 1][lr] = v.y;
        sB[lc + 2][lr] = v.z;
        sB[lc + 3][lr] = v.w;
      }
      __syncthreads();
#pragma unroll
      for (int kk = 0; kk < BK; ++kk) {
        const float4 A0 = *(const float4*)&sA[kk][ty * 4];
        const float4 Bv = *(const float4*)&sB[kk][tx * 4];
        const double a0[4] = {A0.x, A0.y, A0.z, A0.w};
        const double bb[4] = {Bv.x, Bv.y, Bv.z, Bv.w};
#pragma unroll
        for (int i = 0; i < 4; ++i)
#pragma unroll
          for (int j = 0; j < 4; ++j)
            acc[i][j] = fma(a0[i], bb[j], acc[i][j]);
      }
      __syncthreads();
    }
#pragma unroll
    for (int i = 0; i < 4; ++i)
#pragma unroll
      for (int j = 0; j < 4; ++j)
        tile[ty * 4 + i][tx * 4 + j] = acc[i][j] * SIM_SCALE;
    __syncthreads();
    if (tid < BM) {
      for (int j = 0; j < SBN; ++j) {
        const double v = tile[tid][j];
        if (v > tv[TOPK - 1]) {
          double cv = v;
          int ci = col0 + j;
#pragma unroll
          for (int p = 0; p < TOPK; ++p) {
            if (cv > tv[p]) {
              const double t0 = tv[p]; tv[p] = cv; cv = t0;
              const int t1 = ti_[p]; ti_[p] = ci; ci = t1;
            }
          }
        }
      }
    }
    __syncthreads();
  }
  if (tid < BM) {
    const size_t base = ((size_t)(row0 + tid) * NSTRIPS + strip) * TOPK;
#pragma unroll
    for (int p = 0; p < TOPK; ++p) {
      part_v[base + p] = tv[p];
      part_i[base + p] = ti_[p];
    }
  }
}

// ---------------------------------------------------------------------------
// Merge the 16 per-strip top-8 lists per row (strips ascending => lower
// indices first on ties, matching stable top_k). Values double throughout.
// ---------------------------------------------------------------------------
__global__ void merge_topk(const double* __restrict__ part_v,
                           const int* __restrict__ part_i,
                           int* __restrict__ topi)
{
  const int b = blockIdx.x * blockDim.x + threadIdx.x;
  if (b >= B_ROWS) return;
  double tv[TOPK];
  int ti_[TOPK];
#pragma unroll
  for (int p = 0; p < TOPK; ++p) { tv[p] = -1e300; ti_[p] = 0; }
  for (int s = 0; s < NSTRIPS; ++s) {
    const size_t base = ((size_t)b * NSTRIPS + s) * TOPK;
#pragma unroll
    for (int p0 = 0; p0 < TOPK; ++p0) {
      const double v = part_v[base + p0];
      if (v > tv[TOPK - 1]) {
        double cv = v;
        int ci = part_i[base + p0];
#pragma unroll
        for (int p = 0; p < TOPK; ++p) {
          if (cv > tv[p]) {
            const double t0 = tv[p]; tv[p] = cv; cv = t0;
            const int t1 = ti_[p]; ti_[p] = ci; ci = t1;
          }
        }
      }
    }
  }
#pragma unroll
  for (int p = 0; p < TOPK; ++p) topi[(size_t)b * TOPK + p] = ti_[p];
}

// ---------------------------------------------------------------------------
// Gather selected V rows + LayerNorm (biased var, eps=1e-5, affine).
// ---------------------------------------------------------------------------
__global__ __launch_bounds__(256) void gather_ln(
    const float* __restrict__ V, const int* __restrict__ topi,
    const float* __restrict__ gamma, const float* __restrict__ beta,
    float* __restrict__ out)
{
  const int row = blockIdx.x;  // b*8 + rank
  const int tid = threadIdx.x;
  const int idx = topi[row];
  const float* src = V + (size_t)idx * D_DIM;
  const float4 v = *(const float4*)(src + tid * 4);
  float s = v.x + v.y + v.z + v.w;
  float s2 = v.x * v.x + v.y * v.y + v.z * v.z + v.w * v.w;
#pragma unroll
  for (int off = 32; off > 0; off >>= 1) {
    s += __shfl_down(s, off);
    s2 += __shfl_down(s2, off);
  }
  __shared__ float red[8];
  __shared__ float stats[2];
  const int wid = tid >> 6;
  if ((tid & 63) == 0) { red[wid] = s; red[4 + wid] = s2; }
  __syncthreads();
  if (tid == 0) {
    const float S = red[0] + red[1] + red[2] + red[3];
    const float S2 = red[4] + red[5] + red[6] + red[7];
    const float mu = S * (1.0f / D_DIM);
    const float var = S2 * (1.0f / D_DIM) - mu * mu;
    stats[0] = mu;
    stats[1] = rsqrtf(var + 1e-5f);
  }
  __syncthreads();
  const float mu = stats[0], rstd = stats[1];
  const float4 g4 = *(const float4*)(gamma + tid * 4);
  const float4 b4 = *(const float4*)(beta + tid * 4);
  float4 o;
  o.x = (v.x - mu) * rstd * g4.x + b4.x;
  o.y = (v.y - mu) * rstd * g4.y + b4.y;
  o.z = (v.z - mu) * rstd * g4.z + b4.z;
  o.w = (v.w - mu) * rstd * g4.w + b4.w;
  *(float4*)(out + (size_t)row * D_DIM + tid * 4) = o;
}

extern "C" void kernel_launch(void* const* d_in, const int* in_sizes, int n_in,
                              void* d_out, int out_size, void* d_ws, size_t ws_size,
                              hipStream_t stream)
{
  const float* query = (const float*)d_in[0];
  const float* mem   = (const float*)d_in[1];
  const float* Wq    = (const float*)d_in[2];
  const float* bq    = (const float*)d_in[3];
  const float* Wk    = (const float*)d_in[4];
  const float* bk    = (const float*)d_in[5];
  const float* Wv    = (const float*)d_in[6];
  const float* bv    = (const float*)d_in[7];
  const float* gamma = (const float*)d_in[8];
  const float* beta  = (const float*)d_in[9];
  float* out = (float*)d_out;

  char* ws = (char*)d_ws;
  float* q = (float*)ws;        ws += (size_t)B_ROWS * D_DIM * sizeof(float);
  float* K = (float*)ws;        ws += (size_t)M_ROWS * D_DIM * sizeof(float);
  float* V = (float*)ws;        ws += (size_t)M_ROWS * D_DIM * sizeof(float);
  double* part_v = (double*)ws; ws += (size_t)B_ROWS * NSTRIPS * TOPK * sizeof(double);
  int* part_i = (int*)ws;       ws += (size_t)B_ROWS * NSTRIPS * TOPK * sizeof(int);
  int* topi = (int*)ws;

  gemm_nt_bias_f64<<<dim3(B_ROWS / BM, D_DIM / BN), 256, 0, stream>>>(query, Wq, bq, q);
  gemm_nt_bias_f64<<<dim3(M_ROWS / BM, D_DIM / BN), 256, 0, stream>>>(mem, Wk, bk, K);
  gemm_nt_bias_f32<<<dim3(M_ROWS / BM, D_DIM / BN), 256, 0, stream>>>(mem, Wv, bv, V);
  sims_topk_f64<<<dim3(B_ROWS / BM, NSTRIPS), 256, 0, stream>>>(q, K, part_v, part_i);
  merge_topk<<<dim3((B_ROWS + 255) / 256), 256, 0, stream>>>(part_v, part_i, topi);
  gather_ln<<<dim3(B_ROWS * TOPK), 256, 0, stream>>>(V, topi, gamma, beta, out);
}

// Round 3
// 9040.410 us; speedup vs baseline: 1.2639x; 1.2639x over previous
//
#include <hip/hip_runtime.h>
#include <hip/hip_bf16.h>
#include <math.h>

#define D_DIM 1024
#define B_ROWS 4096
#define M_ROWS 32768
#define TOPK 8
#define TOPC 16                          // candidates kept per strip / per row
#define NSTRIPS 16
#define STRIP_COLS (M_ROWS / NSTRIPS)    // 2048

#define BM 128
#define BN 64
#define BK 32

// ---------------------------------------------------------------------------
// out[r][n] = sum_d X[r][d]*W[n][d] + bias[n], fp64 accumulation over fp32
// inputs, rounded once to fp32 on store. Used for q and K (selection path:
// stored values feed the fp64 rescore, so they must match ref to ~1e-7).
// ---------------------------------------------------------------------------
__global__ __launch_bounds__(256) void gemm_nt_bias_f64(
    const float* __restrict__ X, const float* __restrict__ W,
    const float* __restrict__ bias, float* __restrict__ out)
{
  __shared__ float sA[BK][BM + 4];
  __shared__ float sB[BK][BN + 4];
  const int tid = threadIdx.x;
  const int tx = tid & 15, ty = tid >> 4;
  const int row0 = blockIdx.x * BM;
  const int col0 = blockIdx.y * BN;
  const int lr = tid >> 3;         // 0..31
  const int lc = (tid & 7) << 2;   // 0,4,...,28

  double acc[2][4][4];
#pragma unroll
  for (int g = 0; g < 2; ++g)
#pragma unroll
    for (int i = 0; i < 4; ++i)
#pragma unroll
      for (int j = 0; j < 4; ++j) acc[g][i][j] = 0.0;

  for (int k0 = 0; k0 < D_DIM; k0 += BK) {
#pragma unroll
    for (int rr = 0; rr < 4; ++rr) {
      const float4 v = *(const float4*)(X + (size_t)(row0 + lr + 32 * rr) * D_DIM + k0 + lc);
      sA[lc + 0][lr + 32 * rr] = v.x;
      sA[lc + 1][lr + 32 * rr] = v.y;
      sA[lc + 2][lr + 32 * rr] = v.z;
      sA[lc + 3][lr + 32 * rr] = v.w;
    }
#pragma unroll
    for (int rr = 0; rr < 2; ++rr) {
      const float4 v = *(const float4*)(W + (size_t)(col0 + lr + 32 * rr) * D_DIM + k0 + lc);
      sB[lc + 0][lr + 32 * rr] = v.x;
      sB[lc + 1][lr + 32 * rr] = v.y;
      sB[lc + 2][lr + 32 * rr] = v.z;
      sB[lc + 3][lr + 32 * rr] = v.w;
    }
    __syncthreads();
#pragma unroll
    for (int kk = 0; kk < BK; ++kk) {
      const float4 A0 = *(const float4*)&sA[kk][ty * 4];
      const float4 A1 = *(const float4*)&sA[kk][64 + ty * 4];
      const float4 Bv = *(const float4*)&sB[kk][tx * 4];
      const double a0[4] = {A0.x, A0.y, A0.z, A0.w};
      const double a1[4] = {A1.x, A1.y, A1.z, A1.w};
      const double bb[4] = {Bv.x, Bv.y, Bv.z, Bv.w};
#pragma unroll
      for (int i = 0; i < 4; ++i)
#pragma unroll
        for (int j = 0; j < 4; ++j) {
          acc[0][i][j] = fma(a0[i], bb[j], acc[0][i][j]);
          acc[1][i][j] = fma(a1[i], bb[j], acc[1][i][j]);
        }
    }
    __syncthreads();
  }
  const float4 bv4 = *(const float4*)(bias + col0 + tx * 4);
  const double bb[4] = {bv4.x, bv4.y, bv4.z, bv4.w};
#pragma unroll
  for (int g = 0; g < 2; ++g)
#pragma unroll
    for (int i = 0; i < 4; ++i) {
      float4 o;
      o.x = (float)(acc[g][i][0] + bb[0]);
      o.y = (float)(acc[g][i][1] + bb[1]);
      o.z = (float)(acc[g][i][2] + bb[2]);
      o.w = (float)(acc[g][i][3] + bb[3]);
      *(float4*)(out + (size_t)(row0 + g * 64 + ty * 4 + i) * D_DIM + col0 + tx * 4) = o;
    }
}

// ---------------------------------------------------------------------------
// fp32 version for V (values only; 2% output threshold, fp32 error ~1e-6).
// ---------------------------------------------------------------------------
__global__ __launch_bounds__(256) void gemm_nt_bias_f32(
    const float* __restrict__ X, const float* __restrict__ W,
    const float* __restrict__ bias, float* __restrict__ out)
{
  __shared__ float sA[BK][BM + 4];
  __shared__ float sB[BK][BN + 4];
  const int tid = threadIdx.x;
  const int tx = tid & 15, ty = tid >> 4;
  const int row0 = blockIdx.x * BM;
  const int col0 = blockIdx.y * BN;
  const int lr = tid >> 3;
  const int lc = (tid & 7) << 2;

  float acc[2][4][4];
#pragma unroll
  for (int g = 0; g < 2; ++g)
#pragma unroll
    for (int i = 0; i < 4; ++i)
#pragma unroll
      for (int j = 0; j < 4; ++j) acc[g][i][j] = 0.f;

  for (int k0 = 0; k0 < D_DIM; k0 += BK) {
#pragma unroll
    for (int rr = 0; rr < 4; ++rr) {
      const float4 v = *(const float4*)(X + (size_t)(row0 + lr + 32 * rr) * D_DIM + k0 + lc);
      sA[lc + 0][lr + 32 * rr] = v.x;
      sA[lc + 1][lr + 32 * rr] = v.y;
      sA[lc + 2][lr + 32 * rr] = v.z;
      sA[lc + 3][lr + 32 * rr] = v.w;
    }
#pragma unroll
    for (int rr = 0; rr < 2; ++rr) {
      const float4 v = *(const float4*)(W + (size_t)(col0 + lr + 32 * rr) * D_DIM + k0 + lc);
      sB[lc + 0][lr + 32 * rr] = v.x;
      sB[lc + 1][lr + 32 * rr] = v.y;
      sB[lc + 2][lr + 32 * rr] = v.z;
      sB[lc + 3][lr + 32 * rr] = v.w;
    }
    __syncthreads();
#pragma unroll
    for (int kk = 0; kk < BK; ++kk) {
      const float4 A0 = *(const float4*)&sA[kk][ty * 4];
      const float4 A1 = *(const float4*)&sA[kk][64 + ty * 4];
      const float4 Bv = *(const float4*)&sB[kk][tx * 4];
      const float a0[4] = {A0.x, A0.y, A0.z, A0.w};
      const float a1[4] = {A1.x, A1.y, A1.z, A1.w};
      const float bb[4] = {Bv.x, Bv.y, Bv.z, Bv.w};
#pragma unroll
      for (int i = 0; i < 4; ++i)
#pragma unroll
        for (int j = 0; j < 4; ++j) {
          acc[0][i][j] = fmaf(a0[i], bb[j], acc[0][i][j]);
          acc[1][i][j] = fmaf(a1[i], bb[j], acc[1][i][j]);
        }
    }
    __syncthreads();
  }
  const float4 bv4 = *(const float4*)(bias + col0 + tx * 4);
  const float bb[4] = {bv4.x, bv4.y, bv4.z, bv4.w};
#pragma unroll
  for (int g = 0; g < 2; ++g)
#pragma unroll
    for (int i = 0; i < 4; ++i) {
      float4 o;
      o.x = acc[g][i][0] + bb[0];
      o.y = acc[g][i][1] + bb[1];
      o.z = acc[g][i][2] + bb[2];
      o.w = acc[g][i][3] + bb[3];
      *(float4*)(out + (size_t)(row0 + g * 64 + ty * 4 + i) * D_DIM + col0 + tx * 4) = o;
    }
}

// ---------------------------------------------------------------------------
// Fused fp32 sims + per-strip top-16 CANDIDATES. fp32 error (~1e-5) vs the
// 8th->17th order-statistic span (~0.5) makes candidate loss impossible in
// practice; exact ordering is restored by the fp64 rescore pass.
// No scale applied (monotonic; rescore recomputes exactly).
// ---------------------------------------------------------------------------
__global__ __launch_bounds__(256) void sims_topc_f32(
    const float* __restrict__ Q, const float* __restrict__ Km,
    float* __restrict__ part_v, int* __restrict__ part_i)
{
  __shared__ float sA[BK][BM + 4];
  __shared__ float sB[BK][BN + 4];
  __shared__ float tile[BM][BN + 1];
  const int tid = threadIdx.x;
  const int tx = tid & 15, ty = tid >> 4;
  const int row0 = blockIdx.x * BM;
  const int strip = blockIdx.y;
  const int lr = tid >> 3;
  const int lc = (tid & 7) << 2;

  float tv[TOPC];
  int ti_[TOPC];
#pragma unroll
  for (int p = 0; p < TOPC; ++p) { tv[p] = -INFINITY; ti_[p] = 0; }

  for (int ch = 0; ch < STRIP_COLS / BN; ++ch) {
    const int col0 = strip * STRIP_COLS + ch * BN;
    float acc[2][4][4];
#pragma unroll
    for (int g = 0; g < 2; ++g)
#pragma unroll
      for (int i = 0; i < 4; ++i)
#pragma unroll
        for (int j = 0; j < 4; ++j) acc[g][i][j] = 0.f;

    for (int k0 = 0; k0 < D_DIM; k0 += BK) {
#pragma unroll
      for (int rr = 0; rr < 4; ++rr) {
        const float4 v = *(const float4*)(Q + (size_t)(row0 + lr + 32 * rr) * D_DIM + k0 + lc);
        sA[lc + 0][lr + 32 * rr] = v.x;
        sA[lc + 1][lr + 32 * rr] = v.y;
        sA[lc + 2][lr + 32 * rr] = v.z;
        sA[lc + 3][lr + 32 * rr] = v.w;
      }
#pragma unroll
      for (int rr = 0; rr < 2; ++rr) {
        const float4 v = *(const float4*)(Km + (size_t)(col0 + lr + 32 * rr) * D_DIM + k0 + lc);
        sB[lc + 0][lr + 32 * rr] = v.x;
        sB[lc + 1][lr + 32 * rr] = v.y;
        sB[lc + 2][lr + 32 * rr] = v.z;
        sB[lc + 3][lr + 32 * rr] = v.w;
      }
      __syncthreads();
#pragma unroll
      for (int kk = 0; kk < BK; ++kk) {
        const float4 A0 = *(const float4*)&sA[kk][ty * 4];
        const float4 A1 = *(const float4*)&sA[kk][64 + ty * 4];
        const float4 Bv = *(const float4*)&sB[kk][tx * 4];
        const float a0[4] = {A0.x, A0.y, A0.z, A0.w};
        const float a1[4] = {A1.x, A1.y, A1.z, A1.w};
        const float bb[4] = {Bv.x, Bv.y, Bv.z, Bv.w};
#pragma unroll
        for (int i = 0; i < 4; ++i)
#pragma unroll
          for (int j = 0; j < 4; ++j) {
            acc[0][i][j] = fmaf(a0[i], bb[j], acc[0][i][j]);
            acc[1][i][j] = fmaf(a1[i], bb[j], acc[1][i][j]);
          }
      }
      __syncthreads();
    }
#pragma unroll
    for (int g = 0; g < 2; ++g)
#pragma unroll
      for (int i = 0; i < 4; ++i)
#pragma unroll
        for (int j = 0; j < 4; ++j)
          tile[g * 64 + ty * 4 + i][tx * 4 + j] = acc[g][i][j];
    __syncthreads();
    if (tid < BM) {
      for (int j = 0; j < BN; ++j) {
        const float v = tile[tid][j];
        if (v > tv[TOPC - 1]) {
          float cv = v;
          int ci = col0 + j;
#pragma unroll
          for (int p = 0; p < TOPC; ++p) {
            if (cv > tv[p]) {
              const float t0 = tv[p]; tv[p] = cv; cv = t0;
              const int t1 = ti_[p]; ti_[p] = ci; ci = t1;
            }
          }
        }
      }
    }
    __syncthreads();
  }
  if (tid < BM) {
    const size_t base = ((size_t)(row0 + tid) * NSTRIPS + strip) * TOPC;
#pragma unroll
    for (int p = 0; p < TOPC; ++p) {
      part_v[base + p] = tv[p];
      part_i[base + p] = ti_[p];
    }
  }
}

// ---------------------------------------------------------------------------
// Merge 16 per-strip top-16 lists -> 16 candidate indices per row.
// ---------------------------------------------------------------------------
__global__ void merge_cand(const float* __restrict__ part_v,
                           const int* __restrict__ part_i,
                           int* __restrict__ cand)
{
  const int b = blockIdx.x * blockDim.x + threadIdx.x;
  if (b >= B_ROWS) return;
  float tv[TOPC];
  int ti_[TOPC];
#pragma unroll
  for (int p = 0; p < TOPC; ++p) { tv[p] = -INFINITY; ti_[p] = 0; }
  for (int s = 0; s < NSTRIPS; ++s) {
    const size_t base = ((size_t)b * NSTRIPS + s) * TOPC;
#pragma unroll
    for (int p0 = 0; p0 < TOPC; ++p0) {
      const float v = part_v[base + p0];
      if (v > tv[TOPC - 1]) {
        float cv = v;
        int ci = part_i[base + p0];
#pragma unroll
        for (int p = 0; p < TOPC; ++p) {
          if (cv > tv[p]) {
            const float t0 = tv[p]; tv[p] = cv; cv = t0;
            const int t1 = ti_[p]; ti_[p] = ci; ci = t1;
          }
        }
      }
    }
  }
#pragma unroll
  for (int p = 0; p < TOPC; ++p) cand[(size_t)b * TOPC + p] = ti_[p];
}

// ---------------------------------------------------------------------------
// fp64 rescore of the 16 candidates per row + stable top-8 selection
// (value desc, index asc on exact ties == np/lax top_k semantics).
// Block = 1 row (4 waves); wave w rescoresc candidates w, w+4, w+8, w+12.
// ---------------------------------------------------------------------------
__global__ __launch_bounds__(256) void rescore_topk(
    const float* __restrict__ Q, const float* __restrict__ Km,
    const int* __restrict__ cand, int* __restrict__ topi)
{
  const int b = blockIdx.x;
  const int tid = threadIdx.x;
  const int wave = tid >> 6;
  const int lane = tid & 63;

  __shared__ double sval[TOPC];
  __shared__ int sidx[TOPC];

  // each lane covers 16 consecutive elems of the 1024-dim row
  const float* qrow = Q + (size_t)b * D_DIM + lane * 16;
  float4 qv[4];
#pragma unroll
  for (int i = 0; i < 4; ++i) qv[i] = *(const float4*)(qrow + i * 4);

  for (int c = wave; c < TOPC; c += 4) {
    const int ci = cand[(size_t)b * TOPC + c];
    const float* krow = Km + (size_t)ci * D_DIM + lane * 16;
    double acc = 0.0;
#pragma unroll
    for (int i = 0; i < 4; ++i) {
      const float4 kv = *(const float4*)(krow + i * 4);
      acc = fma((double)qv[i].x, (double)kv.x, acc);
      acc = fma((double)qv[i].y, (double)kv.y, acc);
      acc = fma((double)qv[i].z, (double)kv.z, acc);
      acc = fma((double)qv[i].w, (double)kv.w, acc);
    }
#pragma unroll
    for (int off = 32; off > 0; off >>= 1) acc += __shfl_down(acc, off);
    if (lane == 0) { sval[c] = acc; sidx[c] = ci; }
  }
  __syncthreads();

  if (tid == 0) {
    bool used[TOPC];
#pragma unroll
    for (int p = 0; p < TOPC; ++p) used[p] = false;
#pragma unroll
    for (int p = 0; p < TOPK; ++p) {
      int best = -1;
      double bv = 0.0;
      int bi = 0;
      for (int c = 0; c < TOPC; ++c) {
        if (used[c]) continue;
        const double v = sval[c];
        const int ix = sidx[c];
        if (best < 0 || v > bv || (v == bv && ix < bi)) { best = c; bv = v; bi = ix; }
      }
      used[best] = true;
      topi[(size_t)b * TOPK + p] = bi;
    }
  }
}

// ---------------------------------------------------------------------------
// Gather selected V rows + LayerNorm (biased var, eps=1e-5, affine).
// ---------------------------------------------------------------------------
__global__ __launch_bounds__(256) void gather_ln(
    const float* __restrict__ V, const int* __restrict__ topi,
    const float* __restrict__ gamma, const float* __restrict__ beta,
    float* __restrict__ out)
{
  const int row = blockIdx.x;  // b*8 + rank
  const int tid = threadIdx.x;
  const int idx = topi[row];
  const float* src = V + (size_t)idx * D_DIM;
  const float4 v = *(const float4*)(src + tid * 4);
  float s = v.x + v.y + v.z + v.w;
  float s2 = v.x * v.x + v.y * v.y + v.z * v.z + v.w * v.w;
#pragma unroll
  for (int off = 32; off > 0; off >>= 1) {
    s += __shfl_down(s, off);
    s2 += __shfl_down(s2, off);
  }
  __shared__ float red[8];
  __shared__ float stats[2];
  const int wid = tid >> 6;
  if ((tid & 63) == 0) { red[wid] = s; red[4 + wid] = s2; }
  __syncthreads();
  if (tid == 0) {
    const float S = red[0] + red[1] + red[2] + red[3];
    const float S2 = red[4] + red[5] + red[6] + red[7];
    const float mu = S * (1.0f / D_DIM);
    const float var = S2 * (1.0f / D_DIM) - mu * mu;
    stats[0] = mu;
    stats[1] = rsqrtf(var + 1e-5f);
  }
  __syncthreads();
  const float mu = stats[0], rstd = stats[1];
  const float4 g4 = *(const float4*)(gamma + tid * 4);
  const float4 b4 = *(const float4*)(beta + tid * 4);
  float4 o;
  o.x = (v.x - mu) * rstd * g4.x + b4.x;
  o.y = (v.y - mu) * rstd * g4.y + b4.y;
  o.z = (v.z - mu) * rstd * g4.z + b4.z;
  o.w = (v.w - mu) * rstd * g4.w + b4.w;
  *(float4*)(out + (size_t)row * D_DIM + tid * 4) = o;
}

extern "C" void kernel_launch(void* const* d_in, const int* in_sizes, int n_in,
                              void* d_out, int out_size, void* d_ws, size_t ws_size,
                              hipStream_t stream)
{
  const float* query = (const float*)d_in[0];
  const float* mem   = (const float*)d_in[1];
  const float* Wq    = (const float*)d_in[2];
  const float* bq    = (const float*)d_in[3];
  const float* Wk    = (const float*)d_in[4];
  const float* bk    = (const float*)d_in[5];
  const float* Wv    = (const float*)d_in[6];
  const float* bv    = (const float*)d_in[7];
  const float* gamma = (const float*)d_in[8];
  const float* beta  = (const float*)d_in[9];
  float* out = (float*)d_out;

  char* ws = (char*)d_ws;
  float* q = (float*)ws;       ws += (size_t)B_ROWS * D_DIM * sizeof(float);
  float* K = (float*)ws;       ws += (size_t)M_ROWS * D_DIM * sizeof(float);
  float* V = (float*)ws;       ws += (size_t)M_ROWS * D_DIM * sizeof(float);
  float* part_v = (float*)ws;  ws += (size_t)B_ROWS * NSTRIPS * TOPC * sizeof(float);
  int* part_i = (int*)ws;      ws += (size_t)B_ROWS * NSTRIPS * TOPC * sizeof(int);
  int* cand = (int*)ws;        ws += (size_t)B_ROWS * TOPC * sizeof(int);
  int* topi = (int*)ws;

  gemm_nt_bias_f64<<<dim3(B_ROWS / BM, D_DIM / BN), 256, 0, stream>>>(query, Wq, bq, q);
  gemm_nt_bias_f64<<<dim3(M_ROWS / BM, D_DIM / BN), 256, 0, stream>>>(mem, Wk, bk, K);
  gemm_nt_bias_f32<<<dim3(M_ROWS / BM, D_DIM / BN), 256, 0, stream>>>(mem, Wv, bv, V);
  sims_topc_f32<<<dim3(B_ROWS / BM, NSTRIPS), 256, 0, stream>>>(q, K, part_v, part_i);
  merge_cand<<<dim3((B_ROWS + 255) / 256), 256, 0, stream>>>(part_v, part_i, cand);
  rescore_topk<<<dim3(B_ROWS), 256, 0, stream>>>(q, K, cand, topi);
  gather_ln<<<dim3(B_ROWS * TOPK), 256, 0, stream>>>(V, topi, gamma, beta, out);
}

// Round 4
// 5996.812 us; speedup vs baseline: 1.9054x; 1.5075x over previous
//
#include <hip/hip_runtime.h>
#include <hip/hip_bf16.h>
#include <math.h>

#define D_DIM 1024
#define B_ROWS 4096
#define M_ROWS 32768
#define TOPK 8
#define TOPC 16                          // candidates kept per strip / per row
#define NSTRIPS 16
#define STRIP_COLS (M_ROWS / NSTRIPS)    // 2048

#define BM 128
#define BN 64
#define BK 32

typedef __attribute__((ext_vector_type(8))) short bf16x8;
typedef __attribute__((ext_vector_type(4))) float f32x4;

__device__ __forceinline__ unsigned short f32_to_bf16(float f) {
  unsigned int u = __float_as_uint(f);
  unsigned int r = (u + 0x7FFFu + ((u >> 16) & 1u)) >> 16;
  return (unsigned short)r;
}
__device__ __forceinline__ float bf16_to_f32(unsigned short h) {
  return __uint_as_float(((unsigned int)h) << 16);
}
__device__ __forceinline__ void async_copy16(void* lds, const void* g) {
  __builtin_amdgcn_global_load_lds(
      (const __attribute__((address_space(1))) unsigned int*)g,
      (__attribute__((address_space(3))) unsigned int*)lds, 16, 0, 0);
}

// ---------------------------------------------------------------------------
// out[r][n] = sum_d X[r][d]*W[n][d] + bias[n], fp64 accumulation over fp32
// inputs, rounded once to fp32 on store (selection path: these stored values
// feed the fp64 rescore, must match ref to ~1e-7). Also emits bf16 copy for
// the MFMA candidate pass.
// ---------------------------------------------------------------------------
__global__ __launch_bounds__(256) void gemm_nt_bias_f64(
    const float* __restrict__ X, const float* __restrict__ W,
    const float* __restrict__ bias, float* __restrict__ out,
    unsigned short* __restrict__ outbf)
{
  __shared__ float sA[BK][BM + 4];
  __shared__ float sB[BK][BN + 4];
  const int tid = threadIdx.x;
  const int tx = tid & 15, ty = tid >> 4;
  const int row0 = blockIdx.x * BM;
  const int col0 = blockIdx.y * BN;
  const int lr = tid >> 3;         // 0..31
  const int lc = (tid & 7) << 2;   // 0,4,...,28

  double acc[2][4][4];
#pragma unroll
  for (int g = 0; g < 2; ++g)
#pragma unroll
    for (int i = 0; i < 4; ++i)
#pragma unroll
      for (int j = 0; j < 4; ++j) acc[g][i][j] = 0.0;

  for (int k0 = 0; k0 < D_DIM; k0 += BK) {
#pragma unroll
    for (int rr = 0; rr < 4; ++rr) {
      const float4 v = *(const float4*)(X + (size_t)(row0 + lr + 32 * rr) * D_DIM + k0 + lc);
      sA[lc + 0][lr + 32 * rr] = v.x;
      sA[lc + 1][lr + 32 * rr] = v.y;
      sA[lc + 2][lr + 32 * rr] = v.z;
      sA[lc + 3][lr + 32 * rr] = v.w;
    }
#pragma unroll
    for (int rr = 0; rr < 2; ++rr) {
      const float4 v = *(const float4*)(W + (size_t)(col0 + lr + 32 * rr) * D_DIM + k0 + lc);
      sB[lc + 0][lr + 32 * rr] = v.x;
      sB[lc + 1][lr + 32 * rr] = v.y;
      sB[lc + 2][lr + 32 * rr] = v.z;
      sB[lc + 3][lr + 32 * rr] = v.w;
    }
    __syncthreads();
#pragma unroll
    for (int kk = 0; kk < BK; ++kk) {
      const float4 A0 = *(const float4*)&sA[kk][ty * 4];
      const float4 A1 = *(const float4*)&sA[kk][64 + ty * 4];
      const float4 Bv = *(const float4*)&sB[kk][tx * 4];
      const double a0[4] = {A0.x, A0.y, A0.z, A0.w};
      const double a1[4] = {A1.x, A1.y, A1.z, A1.w};
      const double bb[4] = {Bv.x, Bv.y, Bv.z, Bv.w};
#pragma unroll
      for (int i = 0; i < 4; ++i)
#pragma unroll
        for (int j = 0; j < 4; ++j) {
          acc[0][i][j] = fma(a0[i], bb[j], acc[0][i][j]);
          acc[1][i][j] = fma(a1[i], bb[j], acc[1][i][j]);
        }
    }
    __syncthreads();
  }
  const float4 bv4 = *(const float4*)(bias + col0 + tx * 4);
  const double bb[4] = {bv4.x, bv4.y, bv4.z, bv4.w};
#pragma unroll
  for (int g = 0; g < 2; ++g)
#pragma unroll
    for (int i = 0; i < 4; ++i) {
      float4 o;
      o.x = (float)(acc[g][i][0] + bb[0]);
      o.y = (float)(acc[g][i][1] + bb[1]);
      o.z = (float)(acc[g][i][2] + bb[2]);
      o.w = (float)(acc[g][i][3] + bb[3]);
      const size_t base = (size_t)(row0 + g * 64 + ty * 4 + i) * D_DIM + col0 + tx * 4;
      *(float4*)(out + base) = o;
      ushort4 ob;
      ob.x = f32_to_bf16(o.x);
      ob.y = f32_to_bf16(o.y);
      ob.z = f32_to_bf16(o.z);
      ob.w = f32_to_bf16(o.w);
      *(ushort4*)(outbf + base) = ob;
    }
}

// ---------------------------------------------------------------------------
// fp32 version for V (values only; 2% output threshold, fp32 error ~1e-6).
// ---------------------------------------------------------------------------
__global__ __launch_bounds__(256) void gemm_nt_bias_f32(
    const float* __restrict__ X, const float* __restrict__ W,
    const float* __restrict__ bias, float* __restrict__ out)
{
  __shared__ float sA[BK][BM + 4];
  __shared__ float sB[BK][BN + 4];
  const int tid = threadIdx.x;
  const int tx = tid & 15, ty = tid >> 4;
  const int row0 = blockIdx.x * BM;
  const int col0 = blockIdx.y * BN;
  const int lr = tid >> 3;
  const int lc = (tid & 7) << 2;

  float acc[2][4][4];
#pragma unroll
  for (int g = 0; g < 2; ++g)
#pragma unroll
    for (int i = 0; i < 4; ++i)
#pragma unroll
      for (int j = 0; j < 4; ++j) acc[g][i][j] = 0.f;

  for (int k0 = 0; k0 < D_DIM; k0 += BK) {
#pragma unroll
    for (int rr = 0; rr < 4; ++rr) {
      const float4 v = *(const float4*)(X + (size_t)(row0 + lr + 32 * rr) * D_DIM + k0 + lc);
      sA[lc + 0][lr + 32 * rr] = v.x;
      sA[lc + 1][lr + 32 * rr] = v.y;
      sA[lc + 2][lr + 32 * rr] = v.z;
      sA[lc + 3][lr + 32 * rr] = v.w;
    }
#pragma unroll
    for (int rr = 0; rr < 2; ++rr) {
      const float4 v = *(const float4*)(W + (size_t)(col0 + lr + 32 * rr) * D_DIM + k0 + lc);
      sB[lc + 0][lr + 32 * rr] = v.x;
      sB[lc + 1][lr + 32 * rr] = v.y;
      sB[lc + 2][lr + 32 * rr] = v.z;
      sB[lc + 3][lr + 32 * rr] = v.w;
    }
    __syncthreads();
#pragma unroll
    for (int kk = 0; kk < BK; ++kk) {
      const float4 A0 = *(const float4*)&sA[kk][ty * 4];
      const float4 A1 = *(const float4*)&sA[kk][64 + ty * 4];
      const float4 Bv = *(const float4*)&sB[kk][tx * 4];
      const float a0[4] = {A0.x, A0.y, A0.z, A0.w};
      const float a1[4] = {A1.x, A1.y, A1.z, A1.w};
      const float bb[4] = {Bv.x, Bv.y, Bv.z, Bv.w};
#pragma unroll
      for (int i = 0; i < 4; ++i)
#pragma unroll
        for (int j = 0; j < 4; ++j) {
          acc[0][i][j] = fmaf(a0[i], bb[j], acc[0][i][j]);
          acc[1][i][j] = fmaf(a1[i], bb[j], acc[1][i][j]);
        }
    }
    __syncthreads();
  }
  const float4 bv4 = *(const float4*)(bias + col0 + tx * 4);
  const float bb[4] = {bv4.x, bv4.y, bv4.z, bv4.w};
#pragma unroll
  for (int g = 0; g < 2; ++g)
#pragma unroll
    for (int i = 0; i < 4; ++i) {
      float4 o;
      o.x = acc[g][i][0] + bb[0];
      o.y = acc[g][i][1] + bb[1];
      o.z = acc[g][i][2] + bb[2];
      o.w = acc[g][i][3] + bb[3];
      *(float4*)(out + (size_t)(row0 + g * 64 + ty * 4 + i) * D_DIM + col0 + tx * 4) = o;
    }
}

// ---------------------------------------------------------------------------
// bf16 MFMA candidate pass (m97 structure): block = 128 rows x 2048-col strip,
// 16 chunks of 128 cols. Per chunk: 128x128 bf16 GEMM (4 waves, 64x64 each,
// 16x16x32 MFMA, global_load_lds staging, 2 barriers/K-step), then acc -> bf16
// LDS tile, then 128 threads maintain register top-16 per row.
// Candidate-set margin >= 8 ranks (~6 unscaled) vs bf16 error <= ~1 => safe.
// ---------------------------------------------------------------------------
#define SBM 128
#define SBN 128
#define SBK 32
#define CH_PER_STRIP (STRIP_COLS / SBN)   // 16
#define CSTR 132                          // bf16 C-tile stride (conflict-benign)

__global__ __launch_bounds__(256) void sims_topc_mfma(
    const unsigned short* __restrict__ Qb, const unsigned short* __restrict__ Kb,
    float* __restrict__ part_v, int* __restrict__ part_i)
{
  __shared__ unsigned short sA[SBM * SBK];      // 8 KB, linear (gload_lds dest)
  __shared__ unsigned short sB[SBN * SBK];      // 8 KB
  __shared__ unsigned short sC[SBM * CSTR];     // 33.8 KB

  const int tid = threadIdx.x;
  const int lane = tid & 63;
  const int wave = tid >> 6;          // 0..3
  const int wr = wave >> 1, wc = wave & 1;
  const int row0 = blockIdx.x * SBM;
  const int strip = blockIdx.y;

  const int st_r = lane >> 2;          // 0..15 row within 16-row segment
  const int st_cb = (lane & 3) * 16;   // byte offset within 64B row

  float tv[TOPC];
  int ti_[TOPC];
#pragma unroll
  for (int p = 0; p < TOPC; ++p) { tv[p] = -INFINITY; ti_[p] = 0; }

  for (int ch = 0; ch < CH_PER_STRIP; ++ch) {
    const int col0 = strip * STRIP_COLS + ch * SBN;
    f32x4 acc[4][4];
#pragma unroll
    for (int m = 0; m < 4; ++m)
#pragma unroll
      for (int n = 0; n < 4; ++n) acc[m][n] = (f32x4){0.f, 0.f, 0.f, 0.f};

    for (int k0 = 0; k0 < D_DIM; k0 += SBK) {
      // stage A and B tiles: per wave 2 segments of 16 rows each (1KB issues)
#pragma unroll
      for (int i = 0; i < 2; ++i) {
        const int seg = wave * 2 + i;
        const int rr = seg * 16 + st_r;
        async_copy16((char*)sA + seg * 1024,
                     (const char*)(Qb + (size_t)(row0 + rr) * D_DIM + k0) + st_cb);
        async_copy16((char*)sB + seg * 1024,
                     (const char*)(Kb + (size_t)(col0 + rr) * D_DIM + k0) + st_cb);
      }
      __syncthreads();   // drains vmcnt (compiler-inserted) — staging visible
      bf16x8 af[4], bfr[4];
#pragma unroll
      for (int m = 0; m < 4; ++m)
        af[m] = *(const bf16x8*)(sA + (wr * 64 + m * 16 + (lane & 15)) * SBK + (lane >> 4) * 8);
#pragma unroll
      for (int n = 0; n < 4; ++n)
        bfr[n] = *(const bf16x8*)(sB + (wc * 64 + n * 16 + (lane & 15)) * SBK + (lane >> 4) * 8);
#pragma unroll
      for (int m = 0; m < 4; ++m)
#pragma unroll
        for (int n = 0; n < 4; ++n)
          acc[m][n] = __builtin_amdgcn_mfma_f32_16x16x32_bf16(af[m], bfr[n], acc[m][n], 0, 0, 0);
      __syncthreads();   // protect sA/sB before next stage
    }

    // acc -> bf16 LDS tile. C/D layout: col=lane&15, row=(lane>>4)*4+reg (m89).
#pragma unroll
    for (int m = 0; m < 4; ++m)
#pragma unroll
      for (int n = 0; n < 4; ++n)
#pragma unroll
        for (int r = 0; r < 4; ++r) {
          const int row = wr * 64 + m * 16 + (lane >> 4) * 4 + r;
          const int col = wc * 64 + n * 16 + (lane & 15);
          sC[row * CSTR + col] = f32_to_bf16(acc[m][n][r]);
        }
    __syncthreads();

    if (tid < SBM) {
      const unsigned short* crow = sC + tid * CSTR;
      for (int j = 0; j < SBN; j += 4) {
        const ushort4 c4 = *(const ushort4*)(crow + j);
        const unsigned short cs[4] = {c4.x, c4.y, c4.z, c4.w};
#pragma unroll
        for (int e = 0; e < 4; ++e) {
          const float v = bf16_to_f32(cs[e]);
          if (v > tv[TOPC - 1]) {
            float cv = v;
            int ci = col0 + j + e;
#pragma unroll
            for (int p = 0; p < TOPC; ++p) {
              if (cv > tv[p]) {
                const float t0 = tv[p]; tv[p] = cv; cv = t0;
                const int t1 = ti_[p]; ti_[p] = ci; ci = t1;
              }
            }
          }
        }
      }
    }
    __syncthreads();
  }
  if (tid < SBM) {
    const size_t base = ((size_t)(row0 + tid) * NSTRIPS + strip) * TOPC;
#pragma unroll
    for (int p = 0; p < TOPC; ++p) {
      part_v[base + p] = tv[p];
      part_i[base + p] = ti_[p];
    }
  }
}

// ---------------------------------------------------------------------------
// Merge 16 per-strip top-16 lists -> 16 candidate indices per row.
// ---------------------------------------------------------------------------
__global__ void merge_cand(const float* __restrict__ part_v,
                           const int* __restrict__ part_i,
                           int* __restrict__ cand)
{
  const int b = blockIdx.x * blockDim.x + threadIdx.x;
  if (b >= B_ROWS) return;
  float tv[TOPC];
  int ti_[TOPC];
#pragma unroll
  for (int p = 0; p < TOPC; ++p) { tv[p] = -INFINITY; ti_[p] = 0; }
  for (int s = 0; s < NSTRIPS; ++s) {
    const size_t base = ((size_t)b * NSTRIPS + s) * TOPC;
#pragma unroll
    for (int p0 = 0; p0 < TOPC; ++p0) {
      const float v = part_v[base + p0];
      if (v > tv[TOPC - 1]) {
        float cv = v;
        int ci = part_i[base + p0];
#pragma unroll
        for (int p = 0; p < TOPC; ++p) {
          if (cv > tv[p]) {
            const float t0 = tv[p]; tv[p] = cv; cv = t0;
            const int t1 = ti_[p]; ti_[p] = ci; ci = t1;
          }
        }
      }
    }
  }
#pragma unroll
  for (int p = 0; p < TOPC; ++p) cand[(size_t)b * TOPC + p] = ti_[p];
}

// ---------------------------------------------------------------------------
// fp64 rescore of the 16 candidates per row + stable top-8 selection
// (value desc, index asc on exact ties == np/lax top_k semantics).
// UNCHANGED from the passing rounds — do not touch.
// ---------------------------------------------------------------------------
__global__ __launch_bounds__(256) void rescore_topk(
    const float* __restrict__ Q, const float* __restrict__ Km,
    const int* __restrict__ cand, int* __restrict__ topi)
{
  const int b = blockIdx.x;
  const int tid = threadIdx.x;
  const int wave = tid >> 6;
  const int lane = tid & 63;

  __shared__ double sval[TOPC];
  __shared__ int sidx[TOPC];

  const float* qrow = Q + (size_t)b * D_DIM + lane * 16;
  float4 qv[4];
#pragma unroll
  for (int i = 0; i < 4; ++i) qv[i] = *(const float4*)(qrow + i * 4);

  for (int c = wave; c < TOPC; c += 4) {
    const int ci = cand[(size_t)b * TOPC + c];
    const float* krow = Km + (size_t)ci * D_DIM + lane * 16;
    double acc = 0.0;
#pragma unroll
    for (int i = 0; i < 4; ++i) {
      const float4 kv = *(const float4*)(krow + i * 4);
      acc = fma((double)qv[i].x, (double)kv.x, acc);
      acc = fma((double)qv[i].y, (double)kv.y, acc);
      acc = fma((double)qv[i].z, (double)kv.z, acc);
      acc = fma((double)qv[i].w, (double)kv.w, acc);
    }
#pragma unroll
    for (int off = 32; off > 0; off >>= 1) acc += __shfl_down(acc, off);
    if (lane == 0) { sval[c] = acc; sidx[c] = ci; }
  }
  __syncthreads();

  if (tid == 0) {
    bool used[TOPC];
#pragma unroll
    for (int p = 0; p < TOPC; ++p) used[p] = false;
#pragma unroll
    for (int p = 0; p < TOPK; ++p) {
      int best = -1;
      double bv = 0.0;
      int bi = 0;
      for (int c = 0; c < TOPC; ++c) {
        if (used[c]) continue;
        const double v = sval[c];
        const int ix = sidx[c];
        if (best < 0 || v > bv || (v == bv && ix < bi)) { best = c; bv = v; bi = ix; }
      }
      used[best] = true;
      topi[(size_t)b * TOPK + p] = bi;
    }
  }
}

// ---------------------------------------------------------------------------
// Gather selected V rows + LayerNorm (biased var, eps=1e-5, affine).
// ---------------------------------------------------------------------------
__global__ __launch_bounds__(256) void gather_ln(
    const float* __restrict__ V, const int* __restrict__ topi,
    const float* __restrict__ gamma, const float* __restrict__ beta,
    float* __restrict__ out)
{
  const int row = blockIdx.x;  // b*8 + rank
  const int tid = threadIdx.x;
  const int idx = topi[row];
  const float* src = V + (size_t)idx * D_DIM;
  const float4 v = *(const float4*)(src + tid * 4);
  float s = v.x + v.y + v.z + v.w;
  float s2 = v.x * v.x + v.y * v.y + v.z * v.z + v.w * v.w;
#pragma unroll
  for (int off = 32; off > 0; off >>= 1) {
    s += __shfl_down(s, off);
    s2 += __shfl_down(s2, off);
  }
  __shared__ float red[8];
  __shared__ float stats[2];
  const int wid = tid >> 6;
  if ((tid & 63) == 0) { red[wid] = s; red[4 + wid] = s2; }
  __syncthreads();
  if (tid == 0) {
    const float S = red[0] + red[1] + red[2] + red[3];
    const float S2 = red[4] + red[5] + red[6] + red[7];
    const float mu = S * (1.0f / D_DIM);
    const float var = S2 * (1.0f / D_DIM) - mu * mu;
    stats[0] = mu;
    stats[1] = rsqrtf(var + 1e-5f);
  }
  __syncthreads();
  const float mu = stats[0], rstd = stats[1];
  const float4 g4 = *(const float4*)(gamma + tid * 4);
  const float4 b4 = *(const float4*)(beta + tid * 4);
  float4 o;
  o.x = (v.x - mu) * rstd * g4.x + b4.x;
  o.y = (v.y - mu) * rstd * g4.y + b4.y;
  o.z = (v.z - mu) * rstd * g4.z + b4.z;
  o.w = (v.w - mu) * rstd * g4.w + b4.w;
  *(float4*)(out + (size_t)row * D_DIM + tid * 4) = o;
}

extern "C" void kernel_launch(void* const* d_in, const int* in_sizes, int n_in,
                              void* d_out, int out_size, void* d_ws, size_t ws_size,
                              hipStream_t stream)
{
  const float* query = (const float*)d_in[0];
  const float* mem   = (const float*)d_in[1];
  const float* Wq    = (const float*)d_in[2];
  const float* bq    = (const float*)d_in[3];
  const float* Wk    = (const float*)d_in[4];
  const float* bk    = (const float*)d_in[5];
  const float* Wv    = (const float*)d_in[6];
  const float* bv    = (const float*)d_in[7];
  const float* gamma = (const float*)d_in[8];
  const float* beta  = (const float*)d_in[9];
  float* out = (float*)d_out;

  char* ws = (char*)d_ws;
  float* q = (float*)ws;       ws += (size_t)B_ROWS * D_DIM * sizeof(float);
  float* K = (float*)ws;       ws += (size_t)M_ROWS * D_DIM * sizeof(float);
  float* V = (float*)ws;       ws += (size_t)M_ROWS * D_DIM * sizeof(float);
  float* part_v = (float*)ws;  ws += (size_t)B_ROWS * NSTRIPS * TOPC * sizeof(float);
  int* part_i = (int*)ws;      ws += (size_t)B_ROWS * NSTRIPS * TOPC * sizeof(int);
  int* cand = (int*)ws;        ws += (size_t)B_ROWS * TOPC * sizeof(int);
  int* topi = (int*)ws;

  // bf16 q/K parked in the (not-yet-written) V region: 64MB + 8MB <= 128MB.
  unsigned short* Kbf = (unsigned short*)V;
  unsigned short* qbf = (unsigned short*)((char*)V + (size_t)M_ROWS * D_DIM * sizeof(unsigned short));

  gemm_nt_bias_f64<<<dim3(B_ROWS / BM, D_DIM / BN), 256, 0, stream>>>(query, Wq, bq, q, qbf);
  gemm_nt_bias_f64<<<dim3(M_ROWS / BM, D_DIM / BN), 256, 0, stream>>>(mem, Wk, bk, K, Kbf);
  sims_topc_mfma<<<dim3(B_ROWS / SBM, NSTRIPS), 256, 0, stream>>>(qbf, Kbf, part_v, part_i);
  merge_cand<<<dim3((B_ROWS + 255) / 256), 256, 0, stream>>>(part_v, part_i, cand);
  rescore_topk<<<dim3(B_ROWS), 256, 0, stream>>>(q, K, cand, topi);
  // V-proj AFTER sims: it overwrites the bf16 buffers parked in V's region.
  gemm_nt_bias_f32<<<dim3(M_ROWS / BM, D_DIM / BN), 256, 0, stream>>>(mem, Wv, bv, V);
  gather_ln<<<dim3(B_ROWS * TOPK), 256, 0, stream>>>(V, topi, gamma, beta, out);
}